// Round 1
// baseline (542.844 us; speedup 1.0000x reference)
//
#include <hip/hip_runtime.h>
#include <hip/hip_bf16.h>

#define NROW 384
#define GD   1935
#define GK   1952     // padded gate dim (61*32)
#define DD   300
#define KP   320      // padded o
#define DP   304      // padded p

// workspace offsets (in floats)
#define OFF_SIG1 0
#define OFF_SIG2 2048
#define OFF_W    4096
#define OFF_XBF  4112      // ushort[2][384][1952]  (749568 floats)
#define OFF_EBT  753680    // ushort[320][1952]     (312320 floats)  E transposed
#define OFF_FC1B 1066000   // ushort[2][320][320]   (102400 floats)
#define OFF_FC3B 1168400   // ushort[304][320]      (48640 floats)
#define OFF_F1B  1217040   // ushort[2][384][320]   (122880 floats)
#define OFF_AB   1339920   // float[2][384][320]    Ahat | Bhat
#define OFF_CD   1585680   // float[2][384][320]    Chat | Dhat

typedef short short8 __attribute__((ext_vector_type(8)));
typedef float floatx4 __attribute__((ext_vector_type(4)));

__device__ inline unsigned short f2bf(float x){
  union { float f; unsigned u; } v; v.f = x;
  unsigned r = v.u + 0x7fffu + ((v.u >> 16) & 1u);
  return (unsigned short)(r >> 16);
}

// sigmoid(gate1/2), softmax(weight_loc)
__global__ void k_prep(const float* g1, const float* g2, const float* wloc, float* ws){
  int t = blockIdx.x * 256 + threadIdx.x;
  if (t < GD) ws[OFF_SIG1 + t] = 1.f / (1.f + expf(-g1[t]));
  else if (t < 2*GD) ws[OFF_SIG2 + t - GD] = 1.f / (1.f + expf(-g2[t - GD]));
  else if (t == 2*GD){
    float a = wloc[0], b = wloc[1];
    float m = fmaxf(a, b);
    float ea = expf(a - m), eb = expf(b - m);
    ws[OFF_W + 0] = ea / (ea + eb);
    ws[OFF_W + 1] = eb / (ea + eb);
  }
}

// all bf16 conversions in one pass
// tasks: Xbf[2][384][1952] | EbfT[320][1952] | fc1bf[2][320][320] | fc3bf[304][320]
#define NX  (2*384*GK)
#define NE  (KP*GK)
#define NF1 (2*KP*KP)
#define NF3 (DP*KP)
__global__ void k_cvt_all(const float* f1, const float* f2, const float* E,
                          const float* fc1w, const float* fc3w, float* ws){
  int t = blockIdx.x * 256 + threadIdx.x;
  unsigned short* xbf  = (unsigned short*)(ws + OFF_XBF);
  unsigned short* ebt  = (unsigned short*)(ws + OFF_EBT);
  unsigned short* f1b  = (unsigned short*)(ws + OFF_FC1B);
  unsigned short* f3b  = (unsigned short*)(ws + OFF_FC3B);
  if (t < NX){
    int z = t / (384*GK); int r = t - z*384*GK;
    int n = r / GK, k = r - n*GK;
    const float* X   = z ? f2 : f1;
    const float* sig = ws + (z ? OFF_SIG2 : OFF_SIG1);
    float v = (k < GD) ? X[n*GD + k] * sig[k] : 0.f;
    xbf[t] = f2bf(v);
  } else if (t < NX + NE){
    int r = t - NX;
    int c = r / GK, k = r - c*GK;
    float v = (k < GD && c < DD) ? E[k*DD + c] : 0.f;
    ebt[r] = f2bf(v);
  } else if (t < NX + NE + NF1){
    int r = t - NX - NE;
    int z = r / (KP*KP); int r2 = r - z*KP*KP;
    int o = r2 / KP, d = r2 - o*KP;
    float v = (o < DD && d < DD) ? fc1w[o*(2*DD) + z*DD + d] : 0.f;
    f1b[r] = f2bf(v);
  } else {
    int r = t - NX - NE - NF1;
    int p = r / KP, k = r - p*KP;
    float v = (p < DD && k < DD) ? fc3w[p*DD + k] : 0.f;
    f3b[r] = f2bf(v);
  }
}

// gated GEMM: f1bf[z][384][320] = Xbf[z][384][1952] @ EbtT[320][1952]^T (bf16 out)
// one 16x16 tile per wave; 480 tiles per z; grid (120, 2) x 256
__global__ __launch_bounds__(256) void k_gg(float* ws){
  int z = blockIdx.y;
  const unsigned short* X   = (const unsigned short*)(ws + OFF_XBF) + z*384*GK;
  const unsigned short* Ebt = (const unsigned short*)(ws + OFF_EBT);
  unsigned short* out       = (unsigned short*)(ws + OFF_F1B) + z*384*KP;
  int t = threadIdx.x, lane = t & 63;
  int id = blockIdx.x * 4 + (t >> 6);      // 0..479
  int mt = id / 20, ct = id - mt*20;
  int col = lane & 15, quad = lane >> 4;
  const unsigned short* ap = X   + (mt*16 + col)*GK + quad*8;
  const unsigned short* bp = Ebt + (ct*16 + col)*GK + quad*8;
  floatx4 acc = (floatx4){0.f,0.f,0.f,0.f};
  for (int kc = 0; kc < 61; ++kc){
    short8 a = *(const short8*)(ap + kc*32);
    short8 b = *(const short8*)(bp + kc*32);
    acc = __builtin_amdgcn_mfma_f32_16x16x32_bf16(a, b, acc, 0, 0, 0);
  }
  int c = ct*16 + col;
  #pragma unroll
  for (int r = 0; r < 4; ++r){
    int m = mt*16 + quad*4 + r;
    out[m*KP + c] = (c < DD) ? f2bf(acc[r]) : (unsigned short)0;
  }
}

// semantic: AB[z][384][320] = w0*(f1bf[z] @ fc1bf[z]^T (+b1 if z==0)); o>=300 -> 0
__global__ __launch_bounds__(256) void k_sem(const float* fc1b, float* ws){
  int z = blockIdx.y;
  const unsigned short* F = (const unsigned short*)(ws + OFF_F1B) + z*384*KP;
  const unsigned short* W = (const unsigned short*)(ws + OFF_FC1B) + z*KP*KP;
  float* out = ws + OFF_AB + z*384*KP;
  float w0 = ws[OFF_W];
  int t = threadIdx.x, lane = t & 63;
  int id = blockIdx.x * 4 + (t >> 6);      // 0..479
  int rt = id / 20, ot = id - rt*20;
  int col = lane & 15, quad = lane >> 4;
  const unsigned short* ap = F + (rt*16 + col)*KP + quad*8;
  const unsigned short* bp = W + (ot*16 + col)*KP + quad*8;
  floatx4 acc = (floatx4){0.f,0.f,0.f,0.f};
  #pragma unroll
  for (int kc = 0; kc < 10; ++kc){
    short8 a = *(const short8*)(ap + kc*32);
    short8 b = *(const short8*)(bp + kc*32);
    acc = __builtin_amdgcn_mfma_f32_16x16x32_bf16(a, b, acc, 0, 0, 0);
  }
  int o = ot*16 + col;
  float bias = (z == 0 && o < DD) ? fc1b[o] : 0.f;
  #pragma unroll
  for (int r = 0; r < 4; ++r){
    int rr = rt*16 + quad*4 + r;
    out[rr*KP + o] = (o < DD) ? w0 * (acc[r] + bias) : 0.f;
  }
}

// spatial: CD[z][384][320] = w1*(box @ fc2 half (+b2 if z==0)); o>=300 -> 0
__global__ void k_spa(const float* box1, const float* box2, const float* fc2w,
                      const float* fc2b, float* ws){
  int z = blockIdx.y;
  const float* bx = z ? box2 : box1;
  float* out = ws + OFF_CD + z*384*KP;
  int joff = z ? 5 : 0;
  float w1 = ws[OFF_W + 1];
  int t = blockIdx.x * 256 + threadIdx.x;  // 384*320 = 122880 = 480*256
  int r = t / KP, o = t - r*KP;
  float v = 0.f;
  if (o < DD){
    const float* b = bx + r * 5;
    const float* wr = fc2w + o * 10 + joff;
    v = b[0]*wr[0] + b[1]*wr[1] + b[2]*wr[2] + b[3]*wr[3] + b[4]*wr[4];
    if (!z) v += fc2b[o];
    v *= w1;
  }
  out[t] = v;
}

// main: out[n][m][p] = sum_o mixed(n,m,o)*fc3[p][o] + fc3b[p]
// NO LDS, NO BARRIERS: the old smix staging was an identity round-trip
// (builder thread t wrote slot t and read slot t back), and the swt staging
// was address-identical to a direct per-lane global load of fc3bf (the 19 KB
// per-kc weight slice lives in L1/L2, shared across waves via cache).
// Each wave independently owns one 16-row m-tile x 304 p for one n.
// block = 256 thr (4 waves = 4 m-tiles = 64 m); grid (6, 384).
__global__ __launch_bounds__(256, 3) void k_main(const float* fc3b, float* out, const float* ws){
  const unsigned short* fc3bf = (const unsigned short*)(ws + OFF_FC3B);
  int t = threadIdx.x;
  int lane = t & 63, wave = t >> 6;
  int col = lane & 15, quad = lane >> 4;
  int n = blockIdx.y;
  int mrow0 = blockIdx.x * 64 + wave * 16;    // this wave's m-tile base
  const float* Ah = ws + OFF_AB + n * KP;
  const float* Bh = ws + OFF_AB + 384 * KP;
  const float* Ch = ws + OFF_CD + n * KP;
  const float* Dh = ws + OFF_CD + 384 * KP;

  int mg = mrow0 + col;                       // A-frag row this lane holds
  const float* pB = Bh + (size_t)mg * KP;
  const float* pD = Dh + (size_t)mg * KP;
  const unsigned short* wbase = fc3bf + col * KP + quad * 8;  // B-frag base

  floatx4 acc[19];
  #pragma unroll
  for (int i = 0; i < 19; ++i) acc[i] = (floatx4){0.f,0.f,0.f,0.f};

  for (int kc = 0; kc < 10; ++kc){
    int kb = kc*32 + quad*8;                  // this lane's k-offset
    union { unsigned short s[8]; short8 v8; } u;
    float4 a0 = *(const float4*)(Ah + kb);
    float4 c0 = *(const float4*)(Ch + kb);
    float4 b0 = *(const float4*)(pB + kb);
    float4 d0 = *(const float4*)(pD + kb);
    u.s[0] = f2bf(fmaxf(a0.x + b0.x, 0.f) + fmaxf(c0.x + d0.x, 0.f));
    u.s[1] = f2bf(fmaxf(a0.y + b0.y, 0.f) + fmaxf(c0.y + d0.y, 0.f));
    u.s[2] = f2bf(fmaxf(a0.z + b0.z, 0.f) + fmaxf(c0.z + d0.z, 0.f));
    u.s[3] = f2bf(fmaxf(a0.w + b0.w, 0.f) + fmaxf(c0.w + d0.w, 0.f));
    float4 a1 = *(const float4*)(Ah + kb + 4);
    float4 c1 = *(const float4*)(Ch + kb + 4);
    float4 b1 = *(const float4*)(pB + kb + 4);
    float4 d1 = *(const float4*)(pD + kb + 4);
    u.s[4] = f2bf(fmaxf(a1.x + b1.x, 0.f) + fmaxf(c1.x + d1.x, 0.f));
    u.s[5] = f2bf(fmaxf(a1.y + b1.y, 0.f) + fmaxf(c1.y + d1.y, 0.f));
    u.s[6] = f2bf(fmaxf(a1.z + b1.z, 0.f) + fmaxf(c1.z + d1.z, 0.f));
    u.s[7] = f2bf(fmaxf(a1.w + b1.w, 0.f) + fmaxf(c1.w + d1.w, 0.f));
    short8 af = u.v8;
    const unsigned short* wk = wbase + kc*32;
    #pragma unroll
    for (int pt = 0; pt < 19; ++pt){
      short8 bf = *(const short8*)(wk + pt*16*KP);
      acc[pt] = __builtin_amdgcn_mfma_f32_16x16x32_bf16(af, bf, acc[pt], 0, 0, 0);
    }
  }

  #pragma unroll
  for (int pt = 0; pt < 19; ++pt){
    int p = pt*16 + col;
    if (p < DD){
      float bias = fc3b[p];
      #pragma unroll
      for (int r = 0; r < 4; ++r){
        int m = mrow0 + quad*4 + r;
        out[((size_t)n * NROW + m) * DD + p] = acc[pt][r] + bias;
      }
    }
  }
}

extern "C" void kernel_launch(void* const* d_in, const int* in_sizes, int n_in,
                              void* d_out, int out_size, void* d_ws, size_t ws_size,
                              hipStream_t stream) {
  const float* feature1 = (const float*)d_in[0];
  const float* box1     = (const float*)d_in[1];
  const float* feature2 = (const float*)d_in[2];
  const float* box2     = (const float*)d_in[3];
  const float* E        = (const float*)d_in[4];
  const float* gate1    = (const float*)d_in[5];
  const float* gate2    = (const float*)d_in[6];
  const float* wloc     = (const float*)d_in[7];
  const float* fc1w     = (const float*)d_in[8];
  const float* fc1b     = (const float*)d_in[9];
  const float* fc2w     = (const float*)d_in[10];
  const float* fc2b     = (const float*)d_in[11];
  const float* fc3w     = (const float*)d_in[12];
  const float* fc3b     = (const float*)d_in[13];
  float* out = (float*)d_out;
  float* ws  = (float*)d_ws;

  hipLaunchKernelGGL(k_prep, dim3(16), dim3(256), 0, stream, gate1, gate2, wloc, ws);
  hipLaunchKernelGGL(k_cvt_all, dim3((NX+NE+NF1+NF3)/256), dim3(256), 0, stream,
                     feature1, feature2, E, fc1w, fc3w, ws);
  hipLaunchKernelGGL(k_gg, dim3(120, 2), dim3(256), 0, stream, ws);
  hipLaunchKernelGGL(k_sem, dim3(120, 2), dim3(256), 0, stream, fc1b, ws);
  hipLaunchKernelGGL(k_spa, dim3(480, 2), dim3(256), 0, stream,
                     box1, box2, fc2w, fc2b, ws);
  hipLaunchKernelGGL(k_main, dim3(6, NROW), dim3(256), 0, stream, fc3b, out, ws);
}

// Round 2
// 357.554 us; speedup vs baseline: 1.5182x; 1.5182x over previous
//
#include <hip/hip_runtime.h>
#include <hip/hip_bf16.h>

#define NROW 384
#define GD   1935
#define GK   1952     // padded gate dim (61*32)
#define DD   300
#define KP   320      // padded o
#define DP   304      // padded p

// workspace offsets (in floats)
#define OFF_SIG1 0
#define OFF_SIG2 2048
#define OFF_W    4096
#define OFF_XBF  4112      // ushort[2][384][1952]  (749568 floats)
#define OFF_EBT  753680    // ushort[320][1952]     (312320 floats)  E transposed
#define OFF_FC1B 1066000   // ushort[2][320][320]   (102400 floats)
#define OFF_FC3B 1168400   // ushort[10][19][64][8] (48640 floats)  fc3 in FRAG ORDER
#define OFF_F1B  1217040   // ushort[2][384][320]   (122880 floats)
#define OFF_AB   1339920   // float[2][384][320]    Ahat | Bhat
#define OFF_CD   1585680   // float[2][384][320]    Chat | Dhat

typedef short short8 __attribute__((ext_vector_type(8)));
typedef float floatx4 __attribute__((ext_vector_type(4)));

__device__ inline unsigned short f2bf(float x){
  union { float f; unsigned u; } v; v.f = x;
  unsigned r = v.u + 0x7fffu + ((v.u >> 16) & 1u);
  return (unsigned short)(r >> 16);
}

// sigmoid(gate1/2), softmax(weight_loc)
__global__ void k_prep(const float* g1, const float* g2, const float* wloc, float* ws){
  int t = blockIdx.x * 256 + threadIdx.x;
  if (t < GD) ws[OFF_SIG1 + t] = 1.f / (1.f + expf(-g1[t]));
  else if (t < 2*GD) ws[OFF_SIG2 + t - GD] = 1.f / (1.f + expf(-g2[t - GD]));
  else if (t == 2*GD){
    float a = wloc[0], b = wloc[1];
    float m = fmaxf(a, b);
    float ea = expf(a - m), eb = expf(b - m);
    ws[OFF_W + 0] = ea / (ea + eb);
    ws[OFF_W + 1] = eb / (ea + eb);
  }
}

// all bf16 conversions in one pass
// tasks: Xbf[2][384][1952] | EbfT[320][1952] | fc1bf[2][320][320] | fc3 FRAG-PACKED
#define NX  (2*384*GK)
#define NE  (KP*GK)
#define NF1 (2*KP*KP)
#define NF3 (DP*KP)      // = 97280 = 10 kc * 19 pt * 64 lane * 8 elem
__global__ void k_cvt_all(const float* f1, const float* f2, const float* E,
                          const float* fc1w, const float* fc3w, float* ws){
  int t = blockIdx.x * 256 + threadIdx.x;
  unsigned short* xbf  = (unsigned short*)(ws + OFF_XBF);
  unsigned short* ebt  = (unsigned short*)(ws + OFF_EBT);
  unsigned short* f1b  = (unsigned short*)(ws + OFF_FC1B);
  unsigned short* f3b  = (unsigned short*)(ws + OFF_FC3B);
  if (t < NX){
    int z = t / (384*GK); int r = t - z*384*GK;
    int n = r / GK, k = r - n*GK;
    const float* X   = z ? f2 : f1;
    const float* sig = ws + (z ? OFF_SIG2 : OFF_SIG1);
    float v = (k < GD) ? X[n*GD + k] * sig[k] : 0.f;
    xbf[t] = f2bf(v);
  } else if (t < NX + NE){
    int r = t - NX;
    int c = r / GK, k = r - c*GK;
    float v = (k < GD && c < DD) ? E[k*DD + c] : 0.f;
    ebt[r] = f2bf(v);
  } else if (t < NX + NE + NF1){
    int r = t - NX - NE;
    int z = r / (KP*KP); int r2 = r - z*KP*KP;
    int o = r2 / KP, d = r2 - o*KP;
    float v = (o < DD && d < DD) ? fc1w[o*(2*DD) + z*DD + d] : 0.f;
    f1b[r] = f2bf(v);
  } else {
    // fc3 weights packed in MFMA B-fragment order:
    // slot r = ((kc*19 + pt)*64 + lane)*8 + e
    // holds fc3w[p = pt*16 + (lane&15)][k = kc*32 + (lane>>4)*8 + e]
    // so k_main's per-(kc,pt) fragment load is one contiguous 1 KiB block.
    int r = t - NX - NE - NF1;
    int e    = r & 7;
    int lane = (r >> 3) & 63;
    int g    = r >> 9;            // 0..189
    int pt   = g % 19, kc = g / 19;
    int col  = lane & 15, quad = lane >> 4;
    int p = pt*16 + col;
    int k = kc*32 + quad*8 + e;
    float v = (p < DD && k < DD) ? fc3w[p*DD + k] : 0.f;
    f3b[r] = f2bf(v);
  }
}

// gated GEMM: f1bf[z][384][320] = Xbf[z][384][1952] @ EbtT[320][1952]^T (bf16 out)
// one 16x16 tile per wave; 480 tiles per z; grid (120, 2) x 256
__global__ __launch_bounds__(256) void k_gg(float* ws){
  int z = blockIdx.y;
  const unsigned short* X   = (const unsigned short*)(ws + OFF_XBF) + z*384*GK;
  const unsigned short* Ebt = (const unsigned short*)(ws + OFF_EBT);
  unsigned short* out       = (unsigned short*)(ws + OFF_F1B) + z*384*KP;
  int t = threadIdx.x, lane = t & 63;
  int id = blockIdx.x * 4 + (t >> 6);      // 0..479
  int mt = id / 20, ct = id - mt*20;
  int col = lane & 15, quad = lane >> 4;
  const unsigned short* ap = X   + (mt*16 + col)*GK + quad*8;
  const unsigned short* bp = Ebt + (ct*16 + col)*GK + quad*8;
  floatx4 acc = (floatx4){0.f,0.f,0.f,0.f};
  for (int kc = 0; kc < 61; ++kc){
    short8 a = *(const short8*)(ap + kc*32);
    short8 b = *(const short8*)(bp + kc*32);
    acc = __builtin_amdgcn_mfma_f32_16x16x32_bf16(a, b, acc, 0, 0, 0);
  }
  int c = ct*16 + col;
  #pragma unroll
  for (int r = 0; r < 4; ++r){
    int m = mt*16 + quad*4 + r;
    out[m*KP + c] = (c < DD) ? f2bf(acc[r]) : (unsigned short)0;
  }
}

// semantic: AB[z][384][320] = w0*(f1bf[z] @ fc1bf[z]^T (+b1 if z==0)); o>=300 -> 0
__global__ __launch_bounds__(256) void k_sem(const float* fc1b, float* ws){
  int z = blockIdx.y;
  const unsigned short* F = (const unsigned short*)(ws + OFF_F1B) + z*384*KP;
  const unsigned short* W = (const unsigned short*)(ws + OFF_FC1B) + z*KP*KP;
  float* out = ws + OFF_AB + z*384*KP;
  float w0 = ws[OFF_W];
  int t = threadIdx.x, lane = t & 63;
  int id = blockIdx.x * 4 + (t >> 6);      // 0..479
  int rt = id / 20, ot = id - rt*20;
  int col = lane & 15, quad = lane >> 4;
  const unsigned short* ap = F + (rt*16 + col)*KP + quad*8;
  const unsigned short* bp = W + (ot*16 + col)*KP + quad*8;
  floatx4 acc = (floatx4){0.f,0.f,0.f,0.f};
  #pragma unroll
  for (int kc = 0; kc < 10; ++kc){
    short8 a = *(const short8*)(ap + kc*32);
    short8 b = *(const short8*)(bp + kc*32);
    acc = __builtin_amdgcn_mfma_f32_16x16x32_bf16(a, b, acc, 0, 0, 0);
  }
  int o = ot*16 + col;
  float bias = (z == 0 && o < DD) ? fc1b[o] : 0.f;
  #pragma unroll
  for (int r = 0; r < 4; ++r){
    int rr = rt*16 + quad*4 + r;
    out[rr*KP + o] = (o < DD) ? w0 * (acc[r] + bias) : 0.f;
  }
}

// spatial: CD[z][384][320] = w1*(box @ fc2 half (+b2 if z==0)); o>=300 -> 0
__global__ void k_spa(const float* box1, const float* box2, const float* fc2w,
                      const float* fc2b, float* ws){
  int z = blockIdx.y;
  const float* bx = z ? box2 : box1;
  float* out = ws + OFF_CD + z*384*KP;
  int joff = z ? 5 : 0;
  float w1 = ws[OFF_W + 1];
  int t = blockIdx.x * 256 + threadIdx.x;  // 384*320 = 122880 = 480*256
  int r = t / KP, o = t - r*KP;
  float v = 0.f;
  if (o < DD){
    const float* b = bx + r * 5;
    const float* wr = fc2w + o * 10 + joff;
    v = b[0]*wr[0] + b[1]*wr[1] + b[2]*wr[2] + b[3]*wr[3] + b[4]*wr[4];
    if (!z) v += fc2b[o];
    v *= w1;
  }
  out[t] = v;
}

// main: out[n][m][p] = sum_o mixed(n,m,o)*fc3[p][o] + fc3b[p]
// No LDS, no barriers (waves independent). Weight B-fragments are loaded from
// the FRAG-PACKED fc3 array: for (kc,pt) the 64 lanes read one contiguous
// 1 KiB block -> single coalesced transaction, L1-resident (19 KB per kc).
// Round-1's direct strided loads (16 cache lines per load instr) were the
// regression cause; this removes the divergence without reintroducing barriers.
// block = 256 thr (4 waves = 4 m-tiles = 64 m); grid (6, 384).
__global__ __launch_bounds__(256, 3) void k_main(const float* fc3b, float* out, const float* ws){
  const unsigned short* fc3p = (const unsigned short*)(ws + OFF_FC3B);
  int t = threadIdx.x;
  int lane = t & 63, wave = t >> 6;
  int col = lane & 15, quad = lane >> 4;
  int n = blockIdx.y;
  int mrow0 = blockIdx.x * 64 + wave * 16;    // this wave's m-tile base
  const float* Ah = ws + OFF_AB + n * KP;
  const float* Bh = ws + OFF_AB + 384 * KP;
  const float* Ch = ws + OFF_CD + n * KP;
  const float* Dh = ws + OFF_CD + 384 * KP;

  int mg = mrow0 + col;                       // A-frag row this lane holds
  const float* pB = Bh + (size_t)mg * KP;
  const float* pD = Dh + (size_t)mg * KP;
  const unsigned short* wlane = fc3p + lane * 8;   // frag-packed base for this lane

  floatx4 acc[19];
  #pragma unroll
  for (int i = 0; i < 19; ++i) acc[i] = (floatx4){0.f,0.f,0.f,0.f};

  for (int kc = 0; kc < 10; ++kc){
    int kb = kc*32 + quad*8;                  // this lane's k-offset
    union { unsigned short s[8]; short8 v8; } u;
    float4 a0 = *(const float4*)(Ah + kb);
    float4 c0 = *(const float4*)(Ch + kb);
    float4 b0 = *(const float4*)(pB + kb);
    float4 d0 = *(const float4*)(pD + kb);
    u.s[0] = f2bf(fmaxf(a0.x + b0.x, 0.f) + fmaxf(c0.x + d0.x, 0.f));
    u.s[1] = f2bf(fmaxf(a0.y + b0.y, 0.f) + fmaxf(c0.y + d0.y, 0.f));
    u.s[2] = f2bf(fmaxf(a0.z + b0.z, 0.f) + fmaxf(c0.z + d0.z, 0.f));
    u.s[3] = f2bf(fmaxf(a0.w + b0.w, 0.f) + fmaxf(c0.w + d0.w, 0.f));
    float4 a1 = *(const float4*)(Ah + kb + 4);
    float4 c1 = *(const float4*)(Ch + kb + 4);
    float4 b1 = *(const float4*)(pB + kb + 4);
    float4 d1 = *(const float4*)(pD + kb + 4);
    u.s[4] = f2bf(fmaxf(a1.x + b1.x, 0.f) + fmaxf(c1.x + d1.x, 0.f));
    u.s[5] = f2bf(fmaxf(a1.y + b1.y, 0.f) + fmaxf(c1.y + d1.y, 0.f));
    u.s[6] = f2bf(fmaxf(a1.z + b1.z, 0.f) + fmaxf(c1.z + d1.z, 0.f));
    u.s[7] = f2bf(fmaxf(a1.w + b1.w, 0.f) + fmaxf(c1.w + d1.w, 0.f));
    short8 af = u.v8;
    const unsigned short* wk = wlane + kc * (19*64*8);   // this kc's packed slice
    #pragma unroll
    for (int pt = 0; pt < 19; ++pt){
      short8 bf = *(const short8*)(wk + pt * (64*8));
      acc[pt] = __builtin_amdgcn_mfma_f32_16x16x32_bf16(af, bf, acc[pt], 0, 0, 0);
    }
  }

  #pragma unroll
  for (int pt = 0; pt < 19; ++pt){
    int p = pt*16 + col;
    if (p < DD){
      float bias = fc3b[p];
      #pragma unroll
      for (int r = 0; r < 4; ++r){
        int m = mrow0 + quad*4 + r;
        out[((size_t)n * NROW + m) * DD + p] = acc[pt][r] + bias;
      }
    }
  }
}

extern "C" void kernel_launch(void* const* d_in, const int* in_sizes, int n_in,
                              void* d_out, int out_size, void* d_ws, size_t ws_size,
                              hipStream_t stream) {
  const float* feature1 = (const float*)d_in[0];
  const float* box1     = (const float*)d_in[1];
  const float* feature2 = (const float*)d_in[2];
  const float* box2     = (const float*)d_in[3];
  const float* E        = (const float*)d_in[4];
  const float* gate1    = (const float*)d_in[5];
  const float* gate2    = (const float*)d_in[6];
  const float* wloc     = (const float*)d_in[7];
  const float* fc1w     = (const float*)d_in[8];
  const float* fc1b     = (const float*)d_in[9];
  const float* fc2w     = (const float*)d_in[10];
  const float* fc2b     = (const float*)d_in[11];
  const float* fc3w     = (const float*)d_in[12];
  const float* fc3b     = (const float*)d_in[13];
  float* out = (float*)d_out;
  float* ws  = (float*)d_ws;

  hipLaunchKernelGGL(k_prep, dim3(16), dim3(256), 0, stream, gate1, gate2, wloc, ws);
  hipLaunchKernelGGL(k_cvt_all, dim3((NX+NE+NF1+NF3)/256), dim3(256), 0, stream,
                     feature1, feature2, E, fc1w, fc3w, ws);
  hipLaunchKernelGGL(k_gg, dim3(120, 2), dim3(256), 0, stream, ws);
  hipLaunchKernelGGL(k_sem, dim3(120, 2), dim3(256), 0, stream, fc1b, ws);
  hipLaunchKernelGGL(k_spa, dim3(480, 2), dim3(256), 0, stream,
                     box1, box2, fc2w, fc2b, ws);
  hipLaunchKernelGGL(k_main, dim3(6, NROW), dim3(256), 0, stream, fc3b, out, ws);
}

// Round 3
// 331.885 us; speedup vs baseline: 1.6356x; 1.0773x over previous
//
#include <hip/hip_runtime.h>
#include <hip/hip_bf16.h>

#define NROW 384
#define GD   1935
#define GK   1952     // padded gate dim (61*32)
#define DD   300
#define KP   320      // padded o
#define DP   304      // padded p

// workspace offsets (in floats)
#define OFF_XBF  4112      // ushort XP[2][24][61][64][8]  frag-packed gated X
#define OFF_EBT  753680    // ushort EP[20][61][64][8]     frag-packed E^T
#define OFF_FC1B 1066000   // ushort[2][320][320]          fc1 plain
#define OFF_FC3B 1168400   // ushort[10][19][64][8]        fc3 frag-packed (kc-major)
#define OFF_F1B  1217040   // ushort[2][384][320]          gated-GEMM out (plain)
#define OFF_AB   1339920   // float: Ahat plain [384][320] | Bhat packed [24][10][64][8]
#define OFF_CD   1585680   // float: Chat plain [384][320] | Dhat packed [24][10][64][8]

typedef short short8 __attribute__((ext_vector_type(8)));
typedef float floatx4 __attribute__((ext_vector_type(4)));

__device__ inline unsigned short f2bf(float x){
  union { float f; unsigned u; } v; v.f = x;
  unsigned r = v.u + 0x7fffu + ((v.u >> 16) & 1u);
  return (unsigned short)(r >> 16);
}

// ---------------------------------------------------------------------------
// k_cvt_all: every bf16 conversion, 8 elems/thread, frag-packed layouts.
//  X:  XP[((z*24+mt)*61+kc)*64+lane][e] = bf16( X[n][k] * sigmoid(g[k]) )
//      n = mt*16 + (lane&15), k = kc*32 + (lane>>4)*8 + e   (sigmoid inlined)
//  E:  EP[((ct*61)+kc)*64+lane][e]     = bf16( E[k][c] ),  c = ct*16+(lane&15)
//  fc1: plain [z][320][320] zero-padded
//  fc3: packed [(kc*19+pt)*64+lane][e] = bf16( fc3w[p][k] )
// ---------------------------------------------------------------------------
#define TX  (2*24*61*64)     // 187392
#define TE  (20*61*64)       // 78080
#define TF1 (2*320*40)       // 25600
#define TF3 (190*64)         // 12160
#define TTOT (TX+TE+TF1+TF3) // 303232
__global__ void k_cvt_all(const float* f1, const float* f2, const float* E,
                          const float* g1, const float* g2,
                          const float* fc1w, const float* fc3w, float* ws){
  int t = blockIdx.x * 256 + threadIdx.x;
  unsigned short* xbf = (unsigned short*)(ws + OFF_XBF);
  unsigned short* ebt = (unsigned short*)(ws + OFF_EBT);
  unsigned short* f1b = (unsigned short*)(ws + OFF_FC1B);
  unsigned short* f3b = (unsigned short*)(ws + OFF_FC3B);
  if (t < TX){
    int lane = t & 63;
    int rem  = t >> 6;            // ((z*24+mt)*61+kc)
    int kc = rem % 61;
    int rem2 = rem / 61;
    int mt = rem2 % 24, z = rem2 / 24;
    const float* X = z ? f2 : f1;
    const float* g = z ? g2 : g1;
    int n  = mt*16 + (lane & 15);
    int k0 = kc*32 + (lane >> 4)*8;
    union { unsigned short s[8]; uint4 v; } u;
    #pragma unroll
    for (int e = 0; e < 8; ++e){
      int k = k0 + e;
      float v = 0.f;
      if (k < GD){
        float sg = 1.f / (1.f + expf(-g[k]));
        v = X[n*GD + k] * sg;
      }
      u.s[e] = f2bf(v);
    }
    *(uint4*)&xbf[(size_t)t * 8] = u.v;
  } else if (t < TX + TE){
    int i = t - TX;
    int lane = i & 63;
    int rem = i >> 6;
    int kc = rem % 61, ct = rem / 61;
    int c  = ct*16 + (lane & 15);
    int k0 = kc*32 + (lane >> 4)*8;
    union { unsigned short s[8]; uint4 v; } u;
    #pragma unroll
    for (int e = 0; e < 8; ++e){
      int k = k0 + e;
      float v = (k < GD && c < DD) ? E[k*DD + c] : 0.f;
      u.s[e] = f2bf(v);
    }
    *(uint4*)&ebt[(size_t)i * 8] = u.v;
  } else if (t < TX + TE + TF1){
    int i = t - TX - TE;
    int d8 = i % 40; int o = (i/40) % 320; int z = i / (40*320);
    int d0 = d8*8;
    union { unsigned short s[8]; uint4 v; } u;
    #pragma unroll
    for (int e = 0; e < 8; ++e){
      int d = d0 + e;
      float v = (o < DD && d < DD) ? fc1w[o*(2*DD) + z*DD + d] : 0.f;
      u.s[e] = f2bf(v);
    }
    *(uint4*)&f1b[(size_t)((z*KP + o)*KP + d0)] = u.v;
  } else if (t < TTOT){
    int i = t - TX - TE - TF1;
    int lane = i & 63; int g = i >> 6;   // g = kc*19 + pt
    int pt = g % 19, kc = g / 19;
    int p  = pt*16 + (lane & 15);
    int k0 = kc*32 + (lane >> 4)*8;
    union { unsigned short s[8]; uint4 v; } u;
    #pragma unroll
    for (int e = 0; e < 8; ++e){
      int k = k0 + e;
      float v = (p < DD && k < DD) ? fc3w[p*DD + k] : 0.f;
      u.s[e] = f2bf(v);
    }
    *(uint4*)&f3b[(size_t)i * 8] = u.v;
  }
}

// ---------------------------------------------------------------------------
// gated GEMM: F[z][384][320] = X @ E ; frag-packed inputs -> contiguous 1 KB
// wave-loads per kc (was 32 scattered lines). One 16x16 tile per wave.
// ---------------------------------------------------------------------------
__global__ __launch_bounds__(256) void k_gg(float* ws){
  int z = blockIdx.y;
  const unsigned short* XP = (const unsigned short*)(ws + OFF_XBF) + (size_t)z*24*61*512;
  const unsigned short* EP = (const unsigned short*)(ws + OFF_EBT);
  unsigned short* out      = (unsigned short*)(ws + OFF_F1B) + z*384*KP;
  int t = threadIdx.x, lane = t & 63;
  int id = blockIdx.x * 4 + (t >> 6);      // 0..479
  int mt = id / 20, ct = id - mt*20;
  int col = lane & 15, quad = lane >> 4;
  const unsigned short* ap = XP + (size_t)mt*61*512 + lane*8;
  const unsigned short* bp = EP + (size_t)ct*61*512 + lane*8;
  floatx4 acc = (floatx4){0.f,0.f,0.f,0.f};
  for (int kc = 0; kc < 61; ++kc){
    short8 a = *(const short8*)(ap + kc*512);
    short8 b = *(const short8*)(bp + kc*512);
    acc = __builtin_amdgcn_mfma_f32_16x16x32_bf16(a, b, acc, 0, 0, 0);
  }
  int c = ct*16 + col;
  #pragma unroll
  for (int r = 0; r < 4; ++r){
    int m = mt*16 + quad*4 + r;
    out[m*KP + c] = (c < DD) ? f2bf(acc[r]) : (unsigned short)0;
  }
}

// ---------------------------------------------------------------------------
// fused semantic + spatial. softmax(wloc) inlined per-thread.
// z=0 slabs (n-indexed) stored plain; z=1 slabs (m-indexed) stored in
// per-(mt,kc) fragment-packed order for k_main's sequential build loads:
//   packed[(mt*10+kcs)*512 + ((o>>3)&3)*128 + (m&15)*8 + (o&7)]
// ---------------------------------------------------------------------------
__global__ __launch_bounds__(256) void k_sesp(const float* fc1b, const float* box1,
                      const float* box2, const float* fc2w, const float* fc2b,
                      const float* wloc, float* ws){
  int z = blockIdx.y;
  float wa = wloc[0], wbv = wloc[1];
  float mm = fmaxf(wa, wbv);
  float ea = expf(wa - mm), eb = expf(wbv - mm);
  float w0 = ea / (ea + eb), w1 = eb / (ea + eb);
  int t = threadIdx.x;
  if (blockIdx.x < 120){
    // ---- semantic: F[z] @ fc1bf[z]^T, one 16x16 tile per wave ----
    const unsigned short* F = (const unsigned short*)(ws + OFF_F1B) + z*384*KP;
    const unsigned short* W = (const unsigned short*)(ws + OFF_FC1B) + z*KP*KP;
    int lane = t & 63;
    int id = blockIdx.x * 4 + (t >> 6);    // 0..479
    int rt = id / 20, ot = id - rt*20;
    int col = lane & 15, quad = lane >> 4;
    const unsigned short* ap = F + (rt*16 + col)*KP + quad*8;
    const unsigned short* bp = W + (ot*16 + col)*KP + quad*8;
    floatx4 acc = (floatx4){0.f,0.f,0.f,0.f};
    #pragma unroll
    for (int kc = 0; kc < 10; ++kc){
      short8 a = *(const short8*)(ap + kc*32);
      short8 b = *(const short8*)(bp + kc*32);
      acc = __builtin_amdgcn_mfma_f32_16x16x32_bf16(a, b, acc, 0, 0, 0);
    }
    int o = ot*16 + col;
    if (z == 0){
      float bias = (o < DD) ? fc1b[o] : 0.f;
      float* outp = ws + OFF_AB;
      #pragma unroll
      for (int r = 0; r < 4; ++r){
        int rr = rt*16 + quad*4 + r;
        outp[rr*KP + o] = (o < DD) ? w0 * (acc[r] + bias) : 0.f;
      }
    } else {
      float* BP = ws + OFF_AB + 384*KP;
      int kcs = o >> 5, q_o = (o >> 3) & 3, e = o & 7;
      #pragma unroll
      for (int r = 0; r < 4; ++r){
        int lm = quad*4 + r;
        BP[(rt*10 + kcs)*512 + (q_o*16 + lm)*8 + e] = (o < DD) ? w0 * acc[r] : 0.f;
      }
    }
  } else {
    // ---- spatial: box @ fc2 half ----
    int tt = (blockIdx.x - 120) * 256 + t;   // 0..122879
    int r = tt / KP, o = tt - r*KP;
    const float* bx = z ? box2 : box1;
    int joff = z ? 5 : 0;
    float v = 0.f;
    if (o < DD){
      const float* b = bx + r * 5;
      const float* wr = fc2w + o * 10 + joff;
      v = b[0]*wr[0] + b[1]*wr[1] + b[2]*wr[2] + b[3]*wr[3] + b[4]*wr[4];
      if (!z) v += fc2b[o];
      v *= w1;
    }
    if (z == 0) ws[OFF_CD + tt] = v;
    else {
      float* DPp = ws + OFF_CD + 384*KP;
      int mt = r >> 4, lm = r & 15, kcs = o >> 5, q_o = (o >> 3) & 3, e = o & 7;
      DPp[(mt*10 + kcs)*512 + (q_o*16 + lm)*8 + e] = v;
    }
  }
}

// ---------------------------------------------------------------------------
// main: out[n][m][p] = sum_o mixed(n,m,o)*fc3[p][o] + fc3b[p]
// 8 waves/block, wave = one 16-row m-tile; A built in registers from
// plain Ahat/Chat (broadcast) + packed Bhat/Dhat (sequential 2 KB);
// fc3 B-frags staged in LDS once per block per kc (8x L1-traffic cut),
// double-buffered, ONE barrier per kc. Prefetch kc+1 weights into regs
// before compute, ds_write after (T14 issue-early/write-late).
// ---------------------------------------------------------------------------
__global__ __launch_bounds__(512, 3) void k_main(const float* fc3b, float* out, const float* ws){
  __shared__ __align__(16) unsigned short wbuf[2][19*512];   // 2 x 19456 B
  const unsigned short* fc3p = (const unsigned short*)(ws + OFF_FC3B);
  int t = threadIdx.x;
  int lane = t & 63, wave = t >> 6;
  int col = lane & 15, quad = lane >> 4;
  int n = blockIdx.y;
  int mt = blockIdx.x * 8 + wave;            // 0..23
  const float* Ah = ws + OFF_AB + n * KP;
  const float* Ch = ws + OFF_CD + n * KP;
  const float* BP = ws + OFF_AB + 384*KP + (size_t)mt*10*512 + lane*8;
  const float* DPp = ws + OFF_CD + 384*KP + (size_t)mt*10*512 + lane*8;

  floatx4 acc[19];
  #pragma unroll
  for (int i = 0; i < 19; ++i) acc[i] = (floatx4){0.f,0.f,0.f,0.f};

  // stage kc=0 weights (19456 B = 1216 uint4 chunks, 512 threads)
  {
    const uint4* src = (const uint4*)fc3p;
    uint4* dst = (uint4*)&wbuf[0][0];
    dst[t] = src[t];
    dst[t + 512] = src[t + 512];
    if (t < 192) dst[t + 1024] = src[t + 1024];
  }
  __syncthreads();

  for (int kc = 0; kc < 10; ++kc){
    // issue next-slice weight loads early (consumed by ds_write below)
    uint4 s0, s1, s2;
    bool pre = (kc < 9);
    if (pre){
      const uint4* src = (const uint4*)(fc3p + (size_t)(kc+1) * (19*512));
      s0 = src[t]; s1 = src[t + 512];
      if (t < 192) s2 = src[t + 1024];
    }
    // build A-frag in registers
    int kb = kc*32 + quad*8;
    union { unsigned short s[8]; short8 v8; } u;
    float4 a0 = *(const float4*)(Ah + kb);
    float4 c0 = *(const float4*)(Ch + kb);
    float4 b0 = *(const float4*)(BP + kc*512);
    float4 d0 = *(const float4*)(DPp + kc*512);
    float4 a1 = *(const float4*)(Ah + kb + 4);
    float4 c1 = *(const float4*)(Ch + kb + 4);
    float4 b1 = *(const float4*)(BP + kc*512 + 4);
    float4 d1 = *(const float4*)(DPp + kc*512 + 4);
    u.s[0] = f2bf(fmaxf(a0.x + b0.x, 0.f) + fmaxf(c0.x + d0.x, 0.f));
    u.s[1] = f2bf(fmaxf(a0.y + b0.y, 0.f) + fmaxf(c0.y + d0.y, 0.f));
    u.s[2] = f2bf(fmaxf(a0.z + b0.z, 0.f) + fmaxf(c0.z + d0.z, 0.f));
    u.s[3] = f2bf(fmaxf(a0.w + b0.w, 0.f) + fmaxf(c0.w + d0.w, 0.f));
    u.s[4] = f2bf(fmaxf(a1.x + b1.x, 0.f) + fmaxf(c1.x + d1.x, 0.f));
    u.s[5] = f2bf(fmaxf(a1.y + b1.y, 0.f) + fmaxf(c1.y + d1.y, 0.f));
    u.s[6] = f2bf(fmaxf(a1.z + b1.z, 0.f) + fmaxf(c1.z + d1.z, 0.f));
    u.s[7] = f2bf(fmaxf(a1.w + b1.w, 0.f) + fmaxf(c1.w + d1.w, 0.f));
    short8 af = u.v8;
    const unsigned short* wb = wbuf[kc & 1];
    #pragma unroll
    for (int pt = 0; pt < 19; ++pt){
      short8 bf = *(const short8*)(wb + pt*512 + lane*8);
      acc[pt] = __builtin_amdgcn_mfma_f32_16x16x32_bf16(af, bf, acc[pt], 0, 0, 0);
    }
    // write next slice into the other buffer, then single barrier
    if (pre){
      uint4* dst = (uint4*)&wbuf[(kc + 1) & 1][0];
      dst[t] = s0; dst[t + 512] = s1;
      if (t < 192) dst[t + 1024] = s2;
    }
    __syncthreads();
  }

  #pragma unroll
  for (int pt = 0; pt < 19; ++pt){
    int p = pt*16 + col;
    if (p < DD){
      float bias = fc3b[p];
      #pragma unroll
      for (int r = 0; r < 4; ++r){
        int m = mt*16 + quad*4 + r;
        out[((size_t)n * NROW + m) * DD + p] = acc[pt][r] + bias;
      }
    }
  }
}

extern "C" void kernel_launch(void* const* d_in, const int* in_sizes, int n_in,
                              void* d_out, int out_size, void* d_ws, size_t ws_size,
                              hipStream_t stream) {
  const float* feature1 = (const float*)d_in[0];
  const float* box1     = (const float*)d_in[1];
  const float* feature2 = (const float*)d_in[2];
  const float* box2     = (const float*)d_in[3];
  const float* E        = (const float*)d_in[4];
  const float* gate1    = (const float*)d_in[5];
  const float* gate2    = (const float*)d_in[6];
  const float* wloc     = (const float*)d_in[7];
  const float* fc1w     = (const float*)d_in[8];
  const float* fc1b     = (const float*)d_in[9];
  const float* fc2w     = (const float*)d_in[10];
  const float* fc2b     = (const float*)d_in[11];
  const float* fc3w     = (const float*)d_in[12];
  const float* fc3b     = (const float*)d_in[13];
  float* out = (float*)d_out;
  float* ws  = (float*)d_ws;

  hipLaunchKernelGGL(k_cvt_all, dim3((TTOT + 255)/256), dim3(256), 0, stream,
                     feature1, feature2, E, gate1, gate2, fc1w, fc3w, ws);
  hipLaunchKernelGGL(k_gg, dim3(120, 2), dim3(256), 0, stream, ws);
  hipLaunchKernelGGL(k_sesp, dim3(600, 2), dim3(256), 0, stream,
                     fc1b, box1, box2, fc2w, fc2b, wloc, ws);
  hipLaunchKernelGGL(k_main, dim3(3, NROW), dim3(512), 0, stream, fc3b, out, ws);
}